// Round 6
// baseline (2982.908 us; speedup 1.0000x reference)
//
#include <hip/hip_runtime.h>
#include <hip/hip_bf16.h>

// Problem constants (match reference setup_inputs)
#define BG   128          // graphs
#define NPG  1000         // nodes per graph
#define EPG  16000        // edges per graph
#define DIM  128          // feature dim
#define KCL  64           // clusters (only appears as 1/K scale)
#define CCL  10           // classes
#define NN   (BG*NPG)     // 128000 nodes
#define EE   (BG*EPG)     // 2048000 edges
#define SRCMASK 0x1FFFF   // src node id fits in 17 bits (128000 < 2^17)

typedef __attribute__((ext_vector_type(8))) short bf16x8;
typedef __attribute__((ext_vector_type(4))) float f32x4;

__device__ __forceinline__ ushort f2bf(float x) {       // RNE fp32->bf16
    unsigned u = __float_as_uint(x);
    return (ushort)((u + 0x7fffu + ((u >> 16) & 1u)) >> 16);
}
__device__ __forceinline__ float bf2f(ushort h) { return __uint_as_float(((unsigned)h) << 16); }

// ---------------- CSR build ----------------

__global__ __launch_bounds__(256) void count_k(const int* __restrict__ dst, int* __restrict__ cnt) {
    int e = blockIdx.x * 256 + threadIdx.x;
    if (e < EE) atomicAdd(&cnt[dst[e]], 1);
}

// Per-graph exclusive scan of in-degree counts -> CSR offsets (1 block/graph).
// Also emits dinv[n] = rsqrt(deg+1) and the mutable fill cursor copy.
__global__ __launch_bounds__(256) void scan_k(const int* __restrict__ cnt, int* __restrict__ offs,
                                              int* __restrict__ fillpos, float* __restrict__ dinv) {
    int b = blockIdx.x;
    const int nbase = b * NPG;
    const int ebase = b * EPG;
    __shared__ int sdata[256];
    int running = 0;
    for (int j = 0; j < 4; ++j) {
        int i = j * 256 + threadIdx.x;
        int v = (i < NPG) ? cnt[nbase + i] : 0;
        if (i < NPG) dinv[nbase + i] = rsqrtf((float)(v + 1));
        int x = v;
        sdata[threadIdx.x] = x;
        __syncthreads();
        for (int off = 1; off < 256; off <<= 1) {
            int y = (threadIdx.x >= off) ? sdata[threadIdx.x - off] : 0;
            __syncthreads();
            x += y;
            sdata[threadIdx.x] = x;
            __syncthreads();
        }
        int excl = x - v;
        if (i < NPG) {
            int o = ebase + running + excl;
            offs[nbase + i] = o;
            fillpos[nbase + i] = o;
        }
        int total = sdata[255];
        __syncthreads();
        running += total;
    }
}

// bucket word = src | (dst&63)<<24  (row within the dst's 64-node conv block)
__global__ __launch_bounds__(256) void fill_k(const int* __restrict__ src, const int* __restrict__ dst,
                                              int* __restrict__ fillpos, int* __restrict__ bucket) {
    int e = blockIdx.x * 256 + threadIdx.x;
    if (e < EE) {
        int d = dst[e];
        int p = atomicAdd(&fillpos[d], 1);
        bucket[p] = src[e] | ((d & 63) << 24);
    }
}

// ---------------- W pre-transpose + bf16 hi/lo split ----------------
__global__ __launch_bounds__(256) void wconv_k(const float* __restrict__ Wa, const float* __restrict__ Wb,
                                               ushort* __restrict__ Wah, ushort* __restrict__ Wal,
                                               ushort* __restrict__ Wbh, ushort* __restrict__ Wbl) {
    int i = blockIdx.x * 256 + threadIdx.x;
    if (i < DIM * DIM) {
        int col = i >> 7, k = i & 127;
        float a = Wa[k * DIM + col];
        ushort ha = f2bf(a);
        Wah[i] = ha; Wal[i] = f2bf(a - bf2f(ha));
        float b = Wb[k * DIM + col];
        ushort hb = f2bf(b);
        Wbh[i] = hb; Wbl[i] = f2bf(b - bf2f(hb));
    }
}

// ---------------- Fused GCN conv: edge-parallel LDS-atomic agg + split-bf16 MFMA ----------------
// SCALE_SRC=true  (conv1): T[n] = sum_s dinv[s]*X[s] + di*X[n]; agg = di*T; out = di*relu(agg@W+b)
// SCALE_SRC=false (conv2): X pre-scaled; T[n] = sum_s X[s] + X[n]; agg = di*T; POOL sums relu.
template <bool SCALE_SRC, bool POOL>
__global__ __launch_bounds__(256, 5) void conv_k(const float* __restrict__ X,
                                              const ushort* __restrict__ Wh, const ushort* __restrict__ Wl,
                                              const float* __restrict__ dinv, const int* __restrict__ offs,
                                              const int* __restrict__ bucket,
                                              const float* __restrict__ bias,
                                              float* __restrict__ out, float* __restrict__ pooled) {
    __shared__ float T[64 * DIM];     // 32 KiB: fp32 accum tile, then re-laid in place as bf16 hi|lo

    int p = blockIdx.x;                       // 2000 blocks
    int blk = (p & 7) * 250 + (p >> 3);       // XCD swizzle: contiguous 250-block chunk per XCD
    int tid = threadIdx.x;
    const int nodeBase = blk * 64;
    const float4* Xv = (const float4*)X;
    int half = tid >> 5, q = tid & 31;

    // ---- phase 0: self-loop init (8 rows per half-wave, coalesced float4) ----
    for (int i = 0; i < 8; ++i) {
        int row = i * 8 + half;
        int n = nodeBase + row;
        float4 vs = Xv[(size_t)n * 32 + q];
        if (SCALE_SRC) {
            float di = dinv[n];
            vs.x *= di; vs.y *= di; vs.z *= di; vs.w *= di;
        }
        int byte = (row * 512 + q * 16) ^ ((row & 7) << 4);
        *(float4*)((char*)T + byte) = vs;
    }
    __syncthreads();

    // ---- phase 1: edge-parallel gather + ds_add_f32 accumulate (independent edges -> deep MLP) ----
    int o_start = offs[nodeBase];
    int o_end = (nodeBase + 64 < NN) ? offs[nodeBase + 64] : EE;
#pragma unroll 4
    for (int e = o_start + half; e < o_end; e += 8) {
        unsigned w = (unsigned)bucket[e];     // broadcast within half-wave
        int s = w & SRCMASK;
        int row = w >> 24;
        float4 v = Xv[(size_t)s * 32 + q];
        if (SCALE_SRC) {
            float ws = dinv[s];
            v.x *= ws; v.y *= ws; v.z *= ws; v.w *= ws;
        }
        int byte = (row * 512 + q * 16) ^ ((row & 7) << 4);
        float* tp = (float*)((char*)T + byte);
        unsafeAtomicAdd(tp + 0, v.x);
        unsafeAtomicAdd(tp + 1, v.y);
        unsafeAtomicAdd(tp + 2, v.z);
        unsafeAtomicAdd(tp + 3, v.w);
    }
    __syncthreads();

    // ---- phase 1b: in-place fp32 -> bf16 hi/lo (+ outer dinv scale) ----
    // thread t: row r = t>>2, 32 cols starting at (t&3)*32. Read to regs, barrier, rewrite.
    {
        int r = tid >> 2, cb = tid & 3;
        float di = dinv[nodeBase + r];
        float vals[32];
#pragma unroll
        for (int i = 0; i < 8; ++i) {
            int byte = (r * 512 + cb * 128 + i * 16) ^ ((r & 7) << 4);
            float4 v = *(const float4*)((const char*)T + byte);
            vals[i * 4 + 0] = di * v.x; vals[i * 4 + 1] = di * v.y;
            vals[i * 4 + 2] = di * v.z; vals[i * 4 + 3] = di * v.w;
        }
        __syncthreads();
#pragma unroll
        for (int i = 0; i < 8; ++i) {
            int col = cb * 32 + i * 4;
            int byte = (r * 256 + col * 2) ^ ((r & 7) << 4);
            ushort4 hi, lo;
            hi.x = f2bf(vals[i*4+0]); lo.x = f2bf(vals[i*4+0] - bf2f(hi.x));
            hi.y = f2bf(vals[i*4+1]); lo.y = f2bf(vals[i*4+1] - bf2f(hi.y));
            hi.z = f2bf(vals[i*4+2]); lo.z = f2bf(vals[i*4+2] - bf2f(hi.z));
            hi.w = f2bf(vals[i*4+3]); lo.w = f2bf(vals[i*4+3] - bf2f(hi.w));
            *(ushort4*)((char*)T + byte) = hi;                  // hi half: bytes [0, 16K)
            *(ushort4*)((char*)T + 16384 + byte) = lo;          // lo half: bytes [16K, 32K)
        }
    }
    __syncthreads();

    // ---- phase 2: MFMA. wave owns col-tiles {2w,2w+1}, loops 4 row-strips ----
    int wave = tid >> 6, lane = tid & 63;
    int cr = lane & 15, kg = lane >> 4;
    const char* AhB = (const char*)T;
    const char* AlB = (const char*)T + 16384;
    f32x4 acc[2][4];
#pragma unroll
    for (int ct = 0; ct < 2; ++ct)
#pragma unroll
        for (int st = 0; st < 4; ++st) acc[ct][st] = (f32x4)0.f;

#pragma unroll
    for (int t = 0; t < 4; ++t) {
        int kw = t * 32 + kg * 8;
        bf16x8 bh0 = *(const bf16x8*)&Wh[(wave * 32 + cr) * DIM + kw];
        bf16x8 bl0 = *(const bf16x8*)&Wl[(wave * 32 + cr) * DIM + kw];
        bf16x8 bh1 = *(const bf16x8*)&Wh[(wave * 32 + 16 + cr) * DIM + kw];
        bf16x8 bl1 = *(const bf16x8*)&Wl[(wave * 32 + 16 + cr) * DIM + kw];
#pragma unroll
        for (int st = 0; st < 4; ++st) {
            int row = st * 16 + cr;
            int ab = (row * 256 + t * 64 + kg * 16) ^ ((row & 7) << 4);
            bf16x8 ah = *(const bf16x8*)(AhB + ab);
            bf16x8 al = *(const bf16x8*)(AlB + ab);
            acc[0][st] = __builtin_amdgcn_mfma_f32_16x16x32_bf16(ah, bh0, acc[0][st], 0, 0, 0);
            acc[0][st] = __builtin_amdgcn_mfma_f32_16x16x32_bf16(ah, bl0, acc[0][st], 0, 0, 0);
            acc[0][st] = __builtin_amdgcn_mfma_f32_16x16x32_bf16(al, bh0, acc[0][st], 0, 0, 0);
            acc[1][st] = __builtin_amdgcn_mfma_f32_16x16x32_bf16(ah, bh1, acc[1][st], 0, 0, 0);
            acc[1][st] = __builtin_amdgcn_mfma_f32_16x16x32_bf16(ah, bl1, acc[1][st], 0, 0, 0);
            acc[1][st] = __builtin_amdgcn_mfma_f32_16x16x32_bf16(al, bh1, acc[1][st], 0, 0, 0);
        }
    }

    // ---- epilogue ----
    if (!POOL) {
        // conv1: write h_scaled = dinv*relu(acc+bias)
#pragma unroll
        for (int ct = 0; ct < 2; ++ct) {
            int col = wave * 32 + ct * 16 + cr;
            float bb = bias[col];
#pragma unroll
            for (int st = 0; st < 4; ++st)
#pragma unroll
                for (int rr = 0; rr < 4; ++rr) {
                    int n = nodeBase + st * 16 + kg * 4 + rr;
                    out[(size_t)n * DIM + col] = dinv[n] * fmaxf(acc[ct][st][rr] + bb, 0.f);
                }
        }
    } else {
        int g0 = nodeBase / NPG;
        int bnd = (g0 + 1) * NPG;                 // block spans at most graphs g0, g0+1
#pragma unroll
        for (int ct = 0; ct < 2; ++ct) {
            int col = wave * 32 + ct * 16 + cr;
            float bb = bias[col];
            float s1 = 0.f, s2 = 0.f;
#pragma unroll
            for (int st = 0; st < 4; ++st)
#pragma unroll
                for (int rr = 0; rr < 4; ++rr) {
                    int n = nodeBase + st * 16 + kg * 4 + rr;
                    float v = fmaxf(acc[ct][st][rr] + bb, 0.f);
                    if (n < bnd) s1 += v; else s2 += v;
                }
            s1 += __shfl_xor(s1, 16); s1 += __shfl_xor(s1, 32);
            s2 += __shfl_xor(s2, 16); s2 += __shfl_xor(s2, 32);
            if (kg == 0) {
                atomicAdd(&pooled[g0 * DIM + col], s1);
                if (s2 != 0.f) atomicAdd(&pooled[(g0 + 1) * DIM + col], s2);
            }
        }
    }
}

// ---------------- Final MLP head ----------------
__global__ __launch_bounds__(128) void mlp_k(const float* __restrict__ pooled,
                                             const float* __restrict__ W1, const float* __restrict__ b1,
                                             const float* __restrict__ W2, const float* __restrict__ b2,
                                             float* __restrict__ out) {
    int g = blockIdx.x;
    int t = threadIdx.x;
    __shared__ float prow[DIM];
    __shared__ float o1[DIM];
    prow[t] = pooled[g * DIM + t] * (1.0f / (float)KCL);
    __syncthreads();
    float acc = b1[t];
#pragma unroll 8
    for (int d = 0; d < DIM; ++d) acc += prow[d] * W1[d * DIM + t];
    o1[t] = fmaxf(acc, 0.f);
    __syncthreads();
    if (t < CCL) {
        float a = b2[t];
#pragma unroll 8
        for (int cc = 0; cc < DIM; ++cc) a += o1[cc] * W2[cc * CCL + t];
        out[g * CCL + t] = a;
    }
}

extern "C" void kernel_launch(void* const* d_in, const int* in_sizes, int n_in,
                              void* d_out, int out_size, void* d_ws, size_t ws_size,
                              hipStream_t stream) {
    const float* x     = (const float*)d_in[0];
    const int*   ei    = (const int*)d_in[1];      // [2, E]: src then dst
    const float* W_pre = (const float*)d_in[3];
    const float* b_pre = (const float*)d_in[4];
    const float* W_emb = (const float*)d_in[5];
    const float* b_emb = (const float*)d_in[6];
    // W_asn/b_asn provably unused: softmax rows sum to 1, S^T A S unused
    const float* W1    = (const float*)d_in[9];
    const float* b1    = (const float*)d_in[10];
    const float* W2    = (const float*)d_in[11];
    const float* b2    = (const float*)d_in[12];
    float* out = (float*)d_out;

    const int* srcp = ei;
    const int* dstp = ei + EE;

    char* ws = (char*)d_ws;
    size_t off = 0;
    int*    cnt     = (int*)(ws + off);    off += (size_t)NN * 4;
    int*    fillpos = (int*)(ws + off);    off += (size_t)NN * 4;
    float*  dinv    = (float*)(ws + off);  off += (size_t)NN * 4;
    int*    offs    = (int*)(ws + off);    off += (size_t)NN * 4;
    float*  pooled  = (float*)(ws + off);  off += (size_t)BG * DIM * 4;
    ushort* Wph     = (ushort*)(ws + off); off += (size_t)DIM * DIM * 2;
    ushort* Wpl     = (ushort*)(ws + off); off += (size_t)DIM * DIM * 2;
    ushort* Weh     = (ushort*)(ws + off); off += (size_t)DIM * DIM * 2;
    ushort* Wel     = (ushort*)(ws + off); off += (size_t)DIM * DIM * 2;
    int*    bucket  = (int*)(ws + off);    off += (size_t)EE * 4;
    float*  h       = (float*)(ws + off);  off += (size_t)NN * DIM * 4;   // h_scaled
    if (ws_size < off) return;

    hipMemsetAsync(cnt, 0, (size_t)NN * 4, stream);
    hipMemsetAsync(pooled, 0, (size_t)BG * DIM * 4, stream);

    count_k<<<(EE + 255) / 256, 256, 0, stream>>>(dstp, cnt);
    scan_k<<<BG, 256, 0, stream>>>(cnt, offs, fillpos, dinv);
    fill_k<<<(EE + 255) / 256, 256, 0, stream>>>(srcp, dstp, fillpos, bucket);
    wconv_k<<<(DIM * DIM + 255) / 256, 256, 0, stream>>>(W_pre, W_emb, Wph, Wpl, Weh, Wel);

    // conv1: h_scaled = dinv * relu(agg(x) @ W_pre + b_pre)
    conv_k<true, false><<<NN / 64, 256, 0, stream>>>(x, Wph, Wpl, dinv, offs, bucket, b_pre, h, nullptr);
    // conv2 + fused pooling over pre-scaled h
    conv_k<false, true><<<NN / 64, 256, 0, stream>>>(h, Weh, Wel, dinv, offs, bucket, b_emb, nullptr, pooled);

    mlp_k<<<BG, 128, 0, stream>>>(pooled, W1, b1, W2, b2, out);
}

// Round 7
// 576.560 us; speedup vs baseline: 5.1736x; 5.1736x over previous
//
#include <hip/hip_runtime.h>
#include <hip/hip_bf16.h>

// Problem constants (match reference setup_inputs)
#define BG   128          // graphs
#define NPG  1000         // nodes per graph
#define EPG  16000        // edges per graph
#define DIM  128          // feature dim
#define KCL  64           // clusters (only appears as 1/K scale)
#define CCL  10           // classes
#define NN   (BG*NPG)     // 128000 nodes
#define EE   (BG*EPG)     // 2048000 edges

typedef __attribute__((ext_vector_type(8))) short bf16x8;
typedef __attribute__((ext_vector_type(4))) float f32x4;

__device__ __forceinline__ ushort f2bf(float x) {       // RNE fp32->bf16
    unsigned u = __float_as_uint(x);
    return (ushort)((u + 0x7fffu + ((u >> 16) & 1u)) >> 16);
}
__device__ __forceinline__ float bf2f(ushort h) { return __uint_as_float(((unsigned)h) << 16); }

// ---------------- CSR build ----------------
// XCD swizzle: 8000 blocks -> 1000 contiguous blocks (16 graphs) per XCD, so each
// XCD's cnt/fillpos atomic window is 64 KB (L2-resident).

__global__ __launch_bounds__(256) void count_k(const int* __restrict__ dst, int* __restrict__ cnt) {
    int p = blockIdx.x;
    int blk = (p & 7) * 1000 + (p >> 3);
    int e = blk * 256 + threadIdx.x;
    atomicAdd(&cnt[dst[e]], 1);
}

// Per-graph exclusive scan of in-degree counts -> CSR offsets (1 block/graph).
// Also emits dinv[n] = rsqrt(deg+1) and the mutable fill cursor copy.
__global__ __launch_bounds__(256) void scan_k(const int* __restrict__ cnt, int* __restrict__ offs,
                                              int* __restrict__ fillpos, float* __restrict__ dinv) {
    int b = blockIdx.x;
    const int nbase = b * NPG;
    const int ebase = b * EPG;
    __shared__ int sdata[256];
    int running = 0;
    for (int j = 0; j < 4; ++j) {
        int i = j * 256 + threadIdx.x;
        int v = (i < NPG) ? cnt[nbase + i] : 0;
        if (i < NPG) dinv[nbase + i] = rsqrtf((float)(v + 1));
        int x = v;
        sdata[threadIdx.x] = x;
        __syncthreads();
        for (int off = 1; off < 256; off <<= 1) {
            int y = (threadIdx.x >= off) ? sdata[threadIdx.x - off] : 0;
            __syncthreads();
            x += y;
            sdata[threadIdx.x] = x;
            __syncthreads();
        }
        int excl = x - v;
        if (i < NPG) {
            int o = ebase + running + excl;
            offs[nbase + i] = o;
            fillpos[nbase + i] = o;
        }
        int total = sdata[255];
        __syncthreads();
        running += total;
    }
}

__global__ __launch_bounds__(256) void fill_k(const int* __restrict__ src, const int* __restrict__ dst,
                                              int* __restrict__ fillpos, int* __restrict__ bucket) {
    int p = blockIdx.x;
    int blk = (p & 7) * 1000 + (p >> 3);
    int e = blk * 256 + threadIdx.x;
    int d = dst[e];
    int pos = atomicAdd(&fillpos[d], 1);
    bucket[pos] = src[e];
}

// ---------------- W pre-transpose + bf16 hi/lo split ----------------
__global__ __launch_bounds__(256) void wconv_k(const float* __restrict__ Wa, const float* __restrict__ Wb,
                                               ushort* __restrict__ Wah, ushort* __restrict__ Wal,
                                               ushort* __restrict__ Wbh, ushort* __restrict__ Wbl) {
    int i = blockIdx.x * 256 + threadIdx.x;
    if (i < DIM * DIM) {
        int col = i >> 7, k = i & 127;
        float a = Wa[k * DIM + col];
        ushort ha = f2bf(a);
        Wah[i] = ha; Wal[i] = f2bf(a - bf2f(ha));
        float b = Wb[k * DIM + col];
        ushort hb = f2bf(b);
        Wbh[i] = hb; Wbl[i] = f2bf(b - bf2f(hb));
    }
}

// ---------------- Fused GCN conv: agg-first + split-bf16 MFMA ----------------
// SCALE_SRC=true  (conv1): T[n] = sum dinv[s]*X[s] + di*X[n]; agg = di*T; out = di*relu(agg@W+b)
// SCALE_SRC=false (conv2): X pre-scaled: T[n] = sum X[s] + X[n]; agg = di*T; POOL sums relu.
template <bool SCALE_SRC, bool POOL>
__global__ __launch_bounds__(256, 4) void conv_k(const float* __restrict__ X,
                                              const ushort* __restrict__ Wh, const ushort* __restrict__ Wl,
                                              const float* __restrict__ dinv, const int* __restrict__ offs,
                                              const int* __restrict__ cnt, const int* __restrict__ bucket,
                                              const float* __restrict__ bias,
                                              float* __restrict__ out, float* __restrict__ pooled) {
    __shared__ ushort Ah[64 * DIM];   // 16 KiB, XOR-swizzled
    __shared__ ushort Al[64 * DIM];   // 16 KiB

    int p = blockIdx.x;                       // 2000 blocks
    int blk = (p & 7) * 250 + (p >> 3);       // XCD swizzle: contiguous 250-block chunk per XCD
    int tid = threadIdx.x;
    const int nodeBase = blk * 64;
    const float4* Xv = (const float4*)X;
    int half = tid >> 5, q = tid & 31;

    // ---- phase 1: 8 half-waves x 8 rows; 8-deep unrolled gather pipeline with bucket prefetch ----
    for (int i = 0; i < 8; ++i) {
        int row = i * 8 + half;               // row&7 == half
        int n = nodeBase + row;
        float di = dinv[n];
        int o = offs[n];
        int m = cnt[n];
        float4 vs = Xv[(size_t)n * 32 + q];   // self row: issue early

        float ax = 0.f, ay = 0.f, az = 0.f, aw = 0.f;
        int jj = 0;
        if (m >= 8) {
            int sb[8];
#pragma unroll
            for (int k = 0; k < 8; ++k) sb[k] = bucket[o + k];
            while (jj + 8 <= m) {
                int cs[8];
#pragma unroll
                for (int k = 0; k < 8; ++k) cs[k] = sb[k];
                int nxt = jj + 8;
                if (nxt + 8 <= m) {
#pragma unroll
                    for (int k = 0; k < 8; ++k) sb[k] = bucket[o + nxt + k];
                }
                float4 v[8];
#pragma unroll
                for (int k = 0; k < 8; ++k) v[k] = Xv[(size_t)cs[k] * 32 + q];
                if (SCALE_SRC) {
                    float w[8];
#pragma unroll
                    for (int k = 0; k < 8; ++k) w[k] = dinv[cs[k]];
#pragma unroll
                    for (int k = 0; k < 8; ++k) {
                        ax += w[k] * v[k].x; ay += w[k] * v[k].y;
                        az += w[k] * v[k].z; aw += w[k] * v[k].w;
                    }
                } else {
#pragma unroll
                    for (int k = 0; k < 8; ++k) {
                        ax += v[k].x; ay += v[k].y; az += v[k].z; aw += v[k].w;
                    }
                }
                jj = nxt;
            }
        }
        for (; jj < m; ++jj) {
            int s = bucket[o + jj];
            float4 v = Xv[(size_t)s * 32 + q];
            if (SCALE_SRC) {
                float w = dinv[s];
                ax += w * v.x; ay += w * v.y; az += w * v.z; aw += w * v.w;
            } else {
                ax += v.x; ay += v.y; az += v.z; aw += v.w;
            }
        }
        float gx, gy, gz, gw;
        if (SCALE_SRC) {          // conv1: di*(sum + di*self)
            gx = di * (ax + di * vs.x); gy = di * (ay + di * vs.y);
            gz = di * (az + di * vs.z); gw = di * (aw + di * vs.w);
        } else {                  // conv2: di*(sum + self), rows pre-scaled
            gx = di * (ax + vs.x); gy = di * (ay + vs.y);
            gz = di * (az + vs.z); gw = di * (aw + vs.w);
        }

        int byte = (row * 256 + q * 8) ^ ((row & 7) << 4);
        ushort4 hi, lo;
        hi.x = f2bf(gx); lo.x = f2bf(gx - bf2f(hi.x));
        hi.y = f2bf(gy); lo.y = f2bf(gy - bf2f(hi.y));
        hi.z = f2bf(gz); lo.z = f2bf(gz - bf2f(hi.z));
        hi.w = f2bf(gw); lo.w = f2bf(gw - bf2f(hi.w));
        *(ushort4*)((char*)Ah + byte) = hi;
        *(ushort4*)((char*)Al + byte) = lo;
    }
    __syncthreads();

    // ---- phase 2: MFMA. wave owns col-tiles {2w,2w+1}, loops 4 row-strips ----
    int wave = tid >> 6, lane = tid & 63;
    int cr = lane & 15, kg = lane >> 4;
    f32x4 acc[2][4];
#pragma unroll
    for (int ct = 0; ct < 2; ++ct)
#pragma unroll
        for (int st = 0; st < 4; ++st) acc[ct][st] = (f32x4)0.f;

#pragma unroll
    for (int t = 0; t < 4; ++t) {
        int kw = t * 32 + kg * 8;
        bf16x8 bh0 = *(const bf16x8*)&Wh[(wave * 32 + cr) * DIM + kw];
        bf16x8 bl0 = *(const bf16x8*)&Wl[(wave * 32 + cr) * DIM + kw];
        bf16x8 bh1 = *(const bf16x8*)&Wh[(wave * 32 + 16 + cr) * DIM + kw];
        bf16x8 bl1 = *(const bf16x8*)&Wl[(wave * 32 + 16 + cr) * DIM + kw];
#pragma unroll
        for (int st = 0; st < 4; ++st) {
            int row = st * 16 + cr;
            int ab = (row * 256 + t * 64 + kg * 16) ^ ((row & 7) << 4);
            bf16x8 ah = *(const bf16x8*)((const char*)Ah + ab);
            bf16x8 al = *(const bf16x8*)((const char*)Al + ab);
            acc[0][st] = __builtin_amdgcn_mfma_f32_16x16x32_bf16(ah, bh0, acc[0][st], 0, 0, 0);
            acc[0][st] = __builtin_amdgcn_mfma_f32_16x16x32_bf16(ah, bl0, acc[0][st], 0, 0, 0);
            acc[0][st] = __builtin_amdgcn_mfma_f32_16x16x32_bf16(al, bh0, acc[0][st], 0, 0, 0);
            acc[1][st] = __builtin_amdgcn_mfma_f32_16x16x32_bf16(ah, bh1, acc[1][st], 0, 0, 0);
            acc[1][st] = __builtin_amdgcn_mfma_f32_16x16x32_bf16(ah, bl1, acc[1][st], 0, 0, 0);
            acc[1][st] = __builtin_amdgcn_mfma_f32_16x16x32_bf16(al, bh1, acc[1][st], 0, 0, 0);
        }
    }

    // ---- epilogue ----
    if (!POOL) {
        // conv1: write h_scaled = dinv*relu(acc+bias)
#pragma unroll
        for (int ct = 0; ct < 2; ++ct) {
            int col = wave * 32 + ct * 16 + cr;
            float bb = bias[col];
#pragma unroll
            for (int st = 0; st < 4; ++st)
#pragma unroll
                for (int rr = 0; rr < 4; ++rr) {
                    int n = nodeBase + st * 16 + kg * 4 + rr;
                    out[(size_t)n * DIM + col] = dinv[n] * fmaxf(acc[ct][st][rr] + bb, 0.f);
                }
        }
    } else {
        int g0 = nodeBase / NPG;
        int bnd = (g0 + 1) * NPG;                 // block spans at most graphs g0, g0+1
#pragma unroll
        for (int ct = 0; ct < 2; ++ct) {
            int col = wave * 32 + ct * 16 + cr;
            float bb = bias[col];
            float s1 = 0.f, s2 = 0.f;
#pragma unroll
            for (int st = 0; st < 4; ++st)
#pragma unroll
                for (int rr = 0; rr < 4; ++rr) {
                    int n = nodeBase + st * 16 + kg * 4 + rr;
                    float v = fmaxf(acc[ct][st][rr] + bb, 0.f);
                    if (n < bnd) s1 += v; else s2 += v;
                }
            s1 += __shfl_xor(s1, 16); s1 += __shfl_xor(s1, 32);
            s2 += __shfl_xor(s2, 16); s2 += __shfl_xor(s2, 32);
            if (kg == 0) {
                atomicAdd(&pooled[g0 * DIM + col], s1);
                if (s2 != 0.f) atomicAdd(&pooled[(g0 + 1) * DIM + col], s2);
            }
        }
    }
}

// ---------------- Final MLP head ----------------
__global__ __launch_bounds__(128) void mlp_k(const float* __restrict__ pooled,
                                             const float* __restrict__ W1, const float* __restrict__ b1,
                                             const float* __restrict__ W2, const float* __restrict__ b2,
                                             float* __restrict__ out) {
    int g = blockIdx.x;
    int t = threadIdx.x;
    __shared__ float prow[DIM];
    __shared__ float o1[DIM];
    prow[t] = pooled[g * DIM + t] * (1.0f / (float)KCL);
    __syncthreads();
    float acc = b1[t];
#pragma unroll 8
    for (int d = 0; d < DIM; ++d) acc += prow[d] * W1[d * DIM + t];
    o1[t] = fmaxf(acc, 0.f);
    __syncthreads();
    if (t < CCL) {
        float a = b2[t];
#pragma unroll 8
        for (int cc = 0; cc < DIM; ++cc) a += o1[cc] * W2[cc * CCL + t];
        out[g * CCL + t] = a;
    }
}

extern "C" void kernel_launch(void* const* d_in, const int* in_sizes, int n_in,
                              void* d_out, int out_size, void* d_ws, size_t ws_size,
                              hipStream_t stream) {
    const float* x     = (const float*)d_in[0];
    const int*   ei    = (const int*)d_in[1];      // [2, E]: src then dst
    const float* W_pre = (const float*)d_in[3];
    const float* b_pre = (const float*)d_in[4];
    const float* W_emb = (const float*)d_in[5];
    const float* b_emb = (const float*)d_in[6];
    // W_asn/b_asn provably unused: softmax rows sum to 1, S^T A S unused
    const float* W1    = (const float*)d_in[9];
    const float* b1    = (const float*)d_in[10];
    const float* W2    = (const float*)d_in[11];
    const float* b2    = (const float*)d_in[12];
    float* out = (float*)d_out;

    const int* srcp = ei;
    const int* dstp = ei + EE;

    char* ws = (char*)d_ws;
    size_t off = 0;
    int*    cnt     = (int*)(ws + off);    off += (size_t)NN * 4;
    int*    fillpos = (int*)(ws + off);    off += (size_t)NN * 4;
    float*  dinv    = (float*)(ws + off);  off += (size_t)NN * 4;
    int*    offs    = (int*)(ws + off);    off += (size_t)NN * 4;
    float*  pooled  = (float*)(ws + off);  off += (size_t)BG * DIM * 4;
    ushort* Wph     = (ushort*)(ws + off); off += (size_t)DIM * DIM * 2;
    ushort* Wpl     = (ushort*)(ws + off); off += (size_t)DIM * DIM * 2;
    ushort* Weh     = (ushort*)(ws + off); off += (size_t)DIM * DIM * 2;
    ushort* Wel     = (ushort*)(ws + off); off += (size_t)DIM * DIM * 2;
    int*    bucket  = (int*)(ws + off);    off += (size_t)EE * 4;
    float*  h       = (float*)(ws + off);  off += (size_t)NN * DIM * 4;   // h_scaled
    if (ws_size < off) return;

    hipMemsetAsync(cnt, 0, (size_t)NN * 4, stream);
    hipMemsetAsync(pooled, 0, (size_t)BG * DIM * 4, stream);

    count_k<<<EE / 256, 256, 0, stream>>>(dstp, cnt);
    scan_k<<<BG, 256, 0, stream>>>(cnt, offs, fillpos, dinv);
    fill_k<<<EE / 256, 256, 0, stream>>>(srcp, dstp, fillpos, bucket);
    wconv_k<<<(DIM * DIM + 255) / 256, 256, 0, stream>>>(W_pre, W_emb, Wph, Wpl, Weh, Wel);

    // conv1: h_scaled = dinv * relu(agg(x) @ W_pre + b_pre)
    conv_k<true, false><<<NN / 64, 256, 0, stream>>>(x, Wph, Wpl, dinv, offs, cnt, bucket, b_pre, h, nullptr);
    // conv2 + fused pooling over pre-scaled h
    conv_k<false, true><<<NN / 64, 256, 0, stream>>>(h, Weh, Wel, dinv, offs, cnt, bucket, b_emb, nullptr, pooled);

    mlp_k<<<BG, 128, 0, stream>>>(pooled, W1, b1, W2, b2, out);
}